// Round 5
// baseline (264.665 us; speedup 1.0000x reference)
//
#include <hip/hip_runtime.h>
#include <stddef.h>

// Correlation cost volume via bf16 MFMA band-matmul.
// out[b, di*9+dj, h, w] = (1/256) * sum_c x1[b,c,h,w] * x2[b,c,h+di-4,w+dj-4]
// B=4, C=256, H=96, W=192.
//
// R7 resubmit (R4 bench was an infra failure: container acquire died twice;
// kernel never ran; source re-audited for OOB/hang hazards - none found).
//
// R6 -> R7: R6's transpose-both pre-pass (227 MB, ~63us) cost more than the
// LDS-staged main kernel saved, and the main kernel stayed latency-idle
// (MFMA 4.6%, occupancy 31%) because every chunk still convoyed 8 waves
// through two __syncthreads. New structure:
//  - Transpose ONLY x2 into a spatially ZERO-PADDED channel-minor bf16
//    buffer xt2p[b][h+4][w+4][c] (104x208 rows/cols). 113 MB traffic.
//  - Main kernel: NO per-chunk barriers, NO staging LDS. A B-frag is one
//    global_load_dwordx4 per lane straight from L2 (4 q-lanes = one full
//    64B line); padding removes all bounds masks. A-frag from 8 coalesced
//    stride-CHW f32 loads + f2bf (R5 pattern). 9-deep load ILP per wave
//    hides L2 latency; 8 waves/block x 2 blocks/CU provide TLP.
//  - LDS only for the one-shot band-transpose epilogue (23.3 KB).

#define NB 4
#define NC 256
#define HH 96
#define WW 192
#define TW 16
#define TH 4
#define KC 32
#define CHW (HH * WW)

// padded transposed x2: [b][h'][w'][c], h' = h+4 (104), w' = w+4 (208)
#define HP 104
#define WP 208
#define PROW (WP * NC)            // 53248 elems per padded row
#define PIMG (HP * PROW)          // 5,537,792 elems per batch
#define XT2_ELEMS (NB * PIMG)     // 22,151,168
#define XT2_BYTES ((size_t)XT2_ELEMS * 2)   // 44,302,336 B

typedef __attribute__((ext_vector_type(8))) short bf16x8;
typedef __attribute__((ext_vector_type(4))) float f32x4;

__device__ __forceinline__ unsigned short f2bf(float f) {
    union { float f; unsigned u; } c; c.f = f;
    unsigned r = c.u + 0x7FFFu + ((c.u >> 16) & 1u);   // round-to-nearest-even
    return (unsigned short)(r >> 16);
}

// ---------------- pad-frame zero fill (runs before transpose) --------------
// Zeros only the frame: h' in {0..3, 100..103} full width, plus w' in
// {0..3, 196..207} for interior rows. 409,600 uint4 stores = 6.5 MB.
#define NTOP (NB * 8 * WP * 32)            // 212,992 top/bottom tasks
#define NSIDE (NB * HH * 16 * 32)          // 196,608 side tasks
__global__ __launch_bounds__(256) void pad_zero(unsigned short* __restrict__ xt2p)
{
    const uint4 z = make_uint4(0, 0, 0, 0);
    int t = blockIdx.x * 256 + threadIdx.x;
    const int stride = gridDim.x * 256;
    for (; t < NTOP + NSIDE; t += stride) {
        unsigned e;
        if (t < NTOP) {
            const int cg = t & 31;
            const int w  = (t >> 5) % WP;
            const int rr = (t >> 5) / WP;        // 0..31
            const int b  = rr >> 3;
            const int hh = rr & 7;
            const int hp = hh < 4 ? hh : 96 + hh;  // 0..3, 100..103
            e = (unsigned)((b * HP + hp) * WP + w) * NC + cg * 8;
        } else {
            const int u  = t - NTOP;
            const int cg = u & 31;
            const int ws = (u >> 5) & 15;
            const int rr = (u >> 5) >> 4;        // 0..383
            const int b  = rr / HH;
            const int hp = 4 + rr % HH;
            const int wp = ws < 4 ? ws : 192 + ws;  // 0..3, 196..207
            e = (unsigned)((b * HP + hp) * WP + wp) * NC + cg * 8;
        }
        *(uint4*)&xt2p[e] = z;
    }
}

// ---------------- transpose: x2[b][c][h][w] f32 -> xt2p bf16 ---------------
__global__ __launch_bounds__(256) void transpose_x2(
    const float* __restrict__ x2, unsigned short* __restrict__ xt2p)
{
    __shared__ float t[64][65];
    int lin = blockIdx.x;
    const int wt = lin % 3; lin /= 3;
    const int ct = lin & 3; lin >>= 2;
    const int h  = lin % 96; lin /= 96;
    const int b  = lin & 3;
    const int w0 = wt * 64, c0 = ct * 64;

    const int wi = threadIdx.x & 63, c4 = threadIdx.x >> 6;
#pragma unroll
    for (int it = 0; it < 16; ++it) {
        const int c = it * 4 + c4;
        t[c][wi] = x2[((size_t)((b * NC + c0 + c) * HH + h)) * WW + w0 + wi];
    }
    __syncthreads();
#pragma unroll
    for (int it = 0; it < 2; ++it) {
        const int task = it * 256 + threadIdx.x;   // 512 tasks: cg fast, w slow
        const int cg = task & 7;
        const int w  = task >> 3;
        bf16x8 v;
#pragma unroll
        for (int j = 0; j < 8; ++j) v[j] = (short)f2bf(t[cg * 8 + j][w]);
        const unsigned e = (unsigned)((b * HP + h + 4) * WP + (w0 + 4 + w)) * NC
                         + c0 + cg * 8;
        *(bf16x8*)&xt2p[e] = v;
    }
}

// ---------------- main: barrier-free band-matmul ---------------------------
__global__ __launch_bounds__(512, 2) void corr_mfma_g(
    const float* __restrict__ x1,
    const unsigned short* __restrict__ xt2p,
    float* __restrict__ out)
{
    __shared__ float band[TH][9][9][18];   // 23,328 B, epilogue only

    // XCD-aware swizzle: 1152 blocks, 144 consecutive tiles per XCD.
    const int lin = blockIdx.x;
    const int sw  = (lin & 7) * 144 + (lin >> 3);
    const int b   = sw / 288;
    const int t2  = sw - b * 288;
    const int ty  = t2 / 12;
    const int tx  = t2 - ty * 12;

    const int tid  = threadIdx.x;
    const int wv   = tid >> 6;
    const int lane = tid & 63;
    const int col  = lane & 15;       // MFMA m/n 16-index
    const int q    = lane >> 4;       // MFMA k-quad
    const int r    = wv & 3;          // output row within tile
    const int dig  = wv >> 2;         // unit group: 0 -> units 0..8, 1 -> 9..17
    const int w0   = tx * TW;
    const int h0   = ty * TH;
    const int h    = h0 + r;

    f32x4 acc[9];
#pragma unroll
    for (int s = 0; s < 9; ++s) acc[s] = (f32x4)0.0f;

    // per-lane 32-bit element offsets, bumped by += KC per chunk
    unsigned l2[9];
#pragma unroll
    for (int s = 0; s < 9; ++s) {
        const int u    = dig * 9 + s;
        const int di   = u >> 1;
        const int n    = (u & 1) * 16 + col;
        l2[s] = (unsigned)((b * HP + h + di) * WP + (w0 + n)) * NC + q * 8;
    }
    unsigned o1 = (unsigned)((b * NC + q * 8) * HH + h) * WW + w0 + col;

    float pa[8];
#pragma unroll
    for (int j = 0; j < 8; ++j) pa[j] = x1[o1 + j * CHW];
    o1 += KC * CHW;

    for (int ci = 0; ci < 8; ++ci) {
        // issue this chunk's 9 B-frag loads; they fly while we build A
        bf16x8 bfr[9];
#pragma unroll
        for (int s = 0; s < 9; ++s) {
            bfr[s] = *(const bf16x8*)&xt2p[l2[s]];
            l2[s] += KC;
        }
        // A-frag from prefetched f32 (waits only pa: older than bfr loads)
        bf16x8 a;
#pragma unroll
        for (int j = 0; j < 8; ++j) a[j] = (short)f2bf(pa[j]);
        // prefetch next chunk's x1 (lands during MFMA phase)
        if (ci < 7) {
#pragma unroll
            for (int j = 0; j < 8; ++j) pa[j] = x1[o1 + j * CHW];
            o1 += KC * CHW;
        }
        // 9 MFMA, each waiting only its own b128
#pragma unroll
        for (int s = 0; s < 9; ++s)
            acc[s] = __builtin_amdgcn_mfma_f32_16x16x32_bf16(a, bfr[s], acc[s], 0, 0, 0);
    }

    // ---- band extraction: P[m, m+dj] -> band[r][di][dj][m]
    // D layout: col = lane&15 (=n), row m = q*4 + reg.
#pragma unroll
    for (int s = 0; s < 9; ++s) {
        const int u  = dig * 9 + s;
        const int di = u >> 1;
        const int uh = u & 1;
#pragma unroll
        for (int rg = 0; rg < 4; ++rg) {
            int m  = q * 4 + rg;
            int dj = uh * 16 + col - m;
            if (dj >= 0 && dj < 9)
                band[r][di][dj][m] = acc[s][rg];
        }
    }
    __syncthreads();

    // ---- coalesced write-out: 81 channels x 4 rows x 16 w per block
    const float scale = 1.0f / 256.0f;
#pragma unroll
    for (int it = 0; it < 11; ++it) {
        int gi = it * 32 + (tid >> 4);    // gi = combo*4 + row, 324 total
        if (gi < 324) {
            int combo = gi >> 2;
            int row   = gi & 3;
            float v = band[row][combo / 9][combo % 9][tid & 15];
            out[((size_t)((b * 81 + combo) * HH + h0 + row)) * WW + w0 + (tid & 15)] = v * scale;
        }
    }
}

// ---------------- fallback (R5 kernel, used when ws_size is too small) -----
#define NROWS 12
#define NTASK 1152
#define KS 264
#define RS 1096
#define KSTRIDE (KC * CHW)
#define XBI(row, kg, n) ((row) * RS + (kg) * KS + (n) * 8)

__global__ __launch_bounds__(512, 4) void corr_mfma_fb(
    const float* __restrict__ x1, const float* __restrict__ x2,
    float* __restrict__ out)
{
    __shared__ union {
        unsigned short xb[NROWS * RS];
        float band[TH][9][9][18];
    } lds;

    const int lin = blockIdx.x;
    const int sw  = (lin & 7) * 144 + (lin >> 3);
    const int b   = sw / 288;
    const int t2  = sw - b * 288;
    const int ty  = t2 / 12;
    const int tx  = t2 - ty * 12;

    const int tid  = threadIdx.x;
    const int wv   = tid >> 6;
    const int lane = tid & 63;
    const int col  = lane & 15;
    const int q    = lane >> 4;
    const int r    = wv & 3;
    const int dig  = wv >> 2;
    const int w0   = tx * TW;
    const int h0   = ty * TH;
    const int h    = h0 + r;

    f32x4 acc[9];
#pragma unroll
    for (int s = 0; s < 9; ++s) acc[s] = (f32x4)0.0f;

    unsigned o2k[3];
    int      lofk[3];
    bool     okk[3];
    bool     act[3];
#pragma unroll
    for (int k = 0; k < 3; ++k) {
        const int t   = tid + k * 512;
        act[k] = (t < NTASK);
        const int seg = t % 6;
        const int u   = t / 6;
        const int cp  = u & 15;
        const int row = u >> 4;
        const int gh  = h0 - 4 + row;
        const int gw  = w0 - 4 + seg * 4;
        okk[k] = act[k] & (gh >= 0) & (gh < HH) & (gw >= 0) & (gw <= WW - 4);
        const int ghc = gh < 0 ? 0 : (gh > HH - 1 ? HH - 1 : gh);
        const int gwc = gw < 0 ? 0 : gw;
        const int rwc = row > NROWS - 1 ? NROWS - 1 : row;
        o2k[k]  = (unsigned)(((b * NC + cp * 2) * HH + ghc) * WW + gwc);
        lofk[k] = XBI(rwc, cp >> 2, seg * 4) + (cp & 3) * 2;
    }
    unsigned o1 = (unsigned)(((b * NC + q * 8) * HH + h) * WW + w0 + col);

    float pf[24];
    float pa[8];

#define STAGE_LOAD_FB()                                                  \
    {                                                                    \
        _Pragma("unroll")                                                \
        for (int k = 0; k < 3; ++k) {                                    \
            _Pragma("unroll")                                            \
            for (int e = 0; e < 2; ++e) {                                \
                float4 ld = make_float4(0.f, 0.f, 0.f, 0.f);             \
                if (okk[k]) ld = *(const float4*)&x2[o2k[k] + e * CHW];  \
                *(float4*)&pf[(k * 2 + e) * 4] = ld;                     \
            }                                                            \
            o2k[k] += KSTRIDE;                                           \
        }                                                                \
    }

#define X1_LOAD_FB()                                                     \
    {                                                                    \
        _Pragma("unroll")                                                \
        for (int j = 0; j < 8; ++j) pa[j] = x1[o1 + j * CHW];            \
        o1 += KSTRIDE;                                                   \
    }

    STAGE_LOAD_FB();
    X1_LOAD_FB();

    const int rbase = XBI(r, q, col);

    for (int ci = 0; ci < 8; ++ci) {
#pragma unroll
        for (int k = 0; k < 3; ++k) {
            if (act[k]) {
#pragma unroll
                for (int p = 0; p < 4; ++p) {
                    ushort2 v;
                    v.x = f2bf(pf[(k * 2 + 0) * 4 + p]);
                    v.y = f2bf(pf[(k * 2 + 1) * 4 + p]);
                    *(ushort2*)&lds.xb[lofk[k] + p * 8] = v;
                }
            }
        }
        __syncthreads();

        bf16x8 a;
#pragma unroll
        for (int j = 0; j < 8; ++j) a[j] = (short)f2bf(pa[j]);
        if (ci < 7) {
            STAGE_LOAD_FB();
            X1_LOAD_FB();
        }

#pragma unroll
        for (int s = 0; s < 9; ++s) {
            const int u    = dig * 9 + s;
            const int di   = u >> 1;
            const int half = u & 1;
            bf16x8 bb = *(const bf16x8*)&lds.xb[rbase + di * RS + half * 128];
            acc[s] = __builtin_amdgcn_mfma_f32_16x16x32_bf16(a, bb, acc[s], 0, 0, 0);
        }
        __syncthreads();
    }

#pragma unroll
    for (int s = 0; s < 9; ++s) {
        const int u  = dig * 9 + s;
        const int di = u >> 1;
        const int uh = u & 1;
#pragma unroll
        for (int rg = 0; rg < 4; ++rg) {
            int m  = q * 4 + rg;
            int dj = uh * 16 + col - m;
            if (dj >= 0 && dj < 9)
                lds.band[r][di][dj][m] = acc[s][rg];
        }
    }
    __syncthreads();

    const float scale = 1.0f / 256.0f;
#pragma unroll
    for (int it = 0; it < 11; ++it) {
        int gi = it * 32 + (tid >> 4);
        if (gi < 324) {
            int combo = gi >> 2;
            int row   = gi & 3;
            float v = lds.band[row][combo / 9][combo % 9][tid & 15];
            out[((size_t)((b * 81 + combo) * HH + h0 + row)) * WW + w0 + (tid & 15)] = v * scale;
        }
    }
}

extern "C" void kernel_launch(void* const* d_in, const int* in_sizes, int n_in,
                              void* d_out, int out_size, void* d_ws, size_t ws_size,
                              hipStream_t stream) {
    const float* x1 = (const float*)d_in[0];
    const float* x2 = (const float*)d_in[1];
    float* out = (float*)d_out;

    if (ws_size >= XT2_BYTES) {
        unsigned short* xt2p = (unsigned short*)d_ws;
        pad_zero<<<dim3(512), 256, 0, stream>>>(xt2p);
        transpose_x2<<<dim3(4608), 256, 0, stream>>>(x2, xt2p);
        corr_mfma_g<<<dim3(1152), 512, 0, stream>>>(x1, xt2p, out);
    } else {
        corr_mfma_fb<<<dim3(1152), 512, 0, stream>>>(x1, x2, out);
    }
}

// Round 7
// 250.357 us; speedup vs baseline: 1.0571x; 1.0571x over previous
//
#include <hip/hip_runtime.h>
#include <stddef.h>

// Correlation cost volume via bf16 MFMA band-matmul.
// out[b, di*9+dj, h, w] = (1/256) * sum_c x1[b,c,h,w] * x2[b,c,h+di-4,w+dj-4]
// B=4, C=256, H=96, W=192.
//
// R8 resubmit (R6-round bench was an infra failure: GPUAcquisitionTimeout,
// broker at capacity; kernel never ran. Source re-audited - no hazards).
//
// R7 -> R8: R7 (123us) accidentally removed B-prefetch (R6's pfu was 1-deep;
// R7's bfr was 0-deep) AND its direct B-frag loads scattered 64 lanes over
// 16x 512B-apart segments (16 TA transactions/instr vs 4 for contiguous).
// Fix both by packing x2 in MFMA-FRAGMENT-NATIVE tile order in the pre-pass:
//   FT[b][hp][wt][cg] = 1KB tile, elem (q*16+col)*8+j =
//       x2[b][cg*32+q*8+j][hp-4][wt*16+col-4]  (0 if OOB; frame tiles zero)
// Main kernel: every B-frag = ONE contiguous 1KB wave-load (lane*16B).
// No LDS staging, no barriers in loop, no f2bf for B, no bounds masks.
// 1-chunk ping-pong prefetch of B (72 VGPR); x1 f32 gather + f2bf (single
// 8-reg set, prefetched 1 chunk ahead). 256-thr blocks (4 waves: r x dig,
// TH=2) -> 1-wave/SIMD residency granularity at ~148 regs -> 3 waves/SIMD.

#define NB 4
#define NC 256
#define HH 96
#define WW 192
#define TW 16
#define TH 2
#define KC 32
#define CHW (HH * WW)         // 18432

// fragment-tile store: [b][hp 0..103][wt 0..12][cg 0..7] x 1KB
#define HP 104
#define WT 13
#define NCG 8
#define TILE_US 512                          // ushorts per tile (1KB)
#define NTILES (NB * HP * WT * NCG)          // 43,264
#define XT2_BYTES ((size_t)NTILES * 1024)    // 44,302,336 B

typedef __attribute__((ext_vector_type(8))) short bf16x8;
typedef __attribute__((ext_vector_type(4))) float f32x4;

__device__ __forceinline__ unsigned short f2bf(float f) {
    union { float f; unsigned u; } c; c.f = f;
    unsigned r = c.u + 0x7FFFu + ((c.u >> 16) & 1u);   // round-to-nearest-even
    return (unsigned short)(r >> 16);
}

// ---------------- pack: x2[b][c][h][w] f32 -> fragment-native bf16 tiles ---
// One tile per wave. Reads: per j, 4x 64B segments (coalesced). Write: one
// contiguous 1KB wave-store. Frame tiles (hp<4, hp>99, edge cols) zero here
// -> no separate pad kernel.
__global__ __launch_bounds__(256) void pack_x2(
    const float* __restrict__ x2, unsigned short* __restrict__ ft)
{
    const int wv   = threadIdx.x >> 6;
    const int lane = threadIdx.x & 63;
    const int col  = lane & 15;
    const int q    = lane >> 4;

    const int tid0 = blockIdx.x * 4 + wv;    // tile id 0..43263
    int t = tid0;
    const int cg = t & 7;  t >>= 3;
    const int wt = t % WT; t /= WT;
    const int hp = t % HP;
    const int b  = t / HP;

    const int gh = hp - 4;
    const int gw = wt * 16 + col - 4;
    const bool ok = (gh >= 0) & (gh < HH) & (gw >= 0) & (gw < WW);

    bf16x8 v;
    if (ok) {
        const float* src = &x2[(unsigned)((b * NC + cg * 32 + q * 8) * HH + gh) * WW + gw];
#pragma unroll
        for (int j = 0; j < 8; ++j) v[j] = (short)f2bf(src[(size_t)j * CHW]);
    } else {
#pragma unroll
        for (int j = 0; j < 8; ++j) v[j] = 0;
    }
    *(bf16x8*)&ft[(unsigned)tid0 * TILE_US + lane * 8] = v;
}

// ---------------- main: barrier-free band-matmul from fragment tiles -------
__global__ __launch_bounds__(256, 3) void corr_mfma_ft(
    const float* __restrict__ x1,
    const unsigned short* __restrict__ ft,
    float* __restrict__ out)
{
    __shared__ float band[TH][9][9][18];     // 11,664 B, epilogue only

    // XCD-aware swizzle: 2304 blocks, 288 consecutive tiles per XCD.
    const int lin = blockIdx.x;
    const int sw  = (lin & 7) * 288 + (lin >> 3);
    const int b   = sw / 576;                // 576 tiles per batch image
    const int rem = sw - b * 576;
    const int ty  = rem / 12;                // 48 row-pairs
    const int tx  = rem - ty * 12;

    const int tid  = threadIdx.x;
    const int wv   = tid >> 6;               // 4 waves: (r, dig)
    const int lane = tid & 63;
    const int col  = lane & 15;              // MFMA m/n 16-index
    const int q    = lane >> 4;              // MFMA k-quad
    const int r    = wv >> 1;                // output row within tile (0..1)
    const int dig  = wv & 1;                 // unit group: 9 of 18 units
    const int w0   = tx * TW;
    const int h0   = ty * TH;
    const int h    = h0 + r;

    f32x4 acc[9];
#pragma unroll
    for (int s = 0; s < 9; ++s) acc[s] = (f32x4)0.0f;

    // B-frag element offsets (ushorts), one per unit; += TILE_US per chunk
    // (cg is the innermost tile dimension).
    unsigned l2[9];
#pragma unroll
    for (int s = 0; s < 9; ++s) {
        const int u  = dig * 9 + s;
        const int di = u >> 1;
        const int uh = u & 1;
        const unsigned tile = (unsigned)(((b * HP + h + di) * WT + (tx + uh)) * NCG);
        l2[s] = tile * TILE_US + lane * 8;
    }
    unsigned o1 = (unsigned)((b * NC + q * 8) * HH + h) * WW + w0 + col;

    // ---- preload chunk 0
    bf16x8 bfr[2][9];
#pragma unroll
    for (int s = 0; s < 9; ++s) {
        bfr[0][s] = *(const bf16x8*)&ft[l2[s]];
        l2[s] += TILE_US;
    }
    float pa[8];
#pragma unroll
    for (int j = 0; j < 8; ++j) pa[j] = x1[o1 + j * CHW];
    o1 += KC * CHW;

#pragma unroll
    for (int ci = 0; ci < 8; ++ci) {
        const int cur = ci & 1;
        const int nxt = cur ^ 1;
        // issue next chunk's B loads first: they fly across pack + MFMA
        if (ci < 7) {
#pragma unroll
            for (int s = 0; s < 9; ++s) {
                bfr[nxt][s] = *(const bf16x8*)&ft[l2[s]];
                l2[s] += TILE_US;
            }
        }
        // pack A from prefetched x1 (waits this chunk's pa)
        bf16x8 a;
#pragma unroll
        for (int j = 0; j < 8; ++j) a[j] = (short)f2bf(pa[j]);
        // reuse pa regs for next chunk's x1 (WAR ok: pack already read them)
        if (ci < 7) {
#pragma unroll
            for (int j = 0; j < 8; ++j) pa[j] = x1[o1 + j * CHW];
            o1 += KC * CHW;
        }
        // this wave's 9 (di, half) units
#pragma unroll
        for (int s = 0; s < 9; ++s)
            acc[s] = __builtin_amdgcn_mfma_f32_16x16x32_bf16(a, bfr[cur][s], acc[s], 0, 0, 0);
    }

    // ---- band extraction: P[m, m+dj] -> band[r][di][dj][m]
    // D layout: col = lane&15 (=n), row m = q*4 + reg.
#pragma unroll
    for (int s = 0; s < 9; ++s) {
        const int u  = dig * 9 + s;
        const int di = u >> 1;
        const int uh = u & 1;
#pragma unroll
        for (int rg = 0; rg < 4; ++rg) {
            int m  = q * 4 + rg;
            int dj = uh * 16 + col - m;
            if (dj >= 0 && dj < 9)
                band[r][di][dj][m] = acc[s][rg];
        }
    }
    __syncthreads();

    // ---- coalesced write-out: 81 channels x 2 rows x 16 w per block
    const float scale = 1.0f / 256.0f;
#pragma unroll
    for (int it = 0; it < 11; ++it) {
        int gi = it * 16 + (tid >> 4);       // gi = combo*2 + row, 162 total
        if (gi < 162) {
            int combo = gi >> 1;
            int row   = gi & 1;
            float v = band[row][combo / 9][combo % 9][tid & 15];
            out[((size_t)((b * 81 + combo) * HH + h0 + row)) * WW + w0 + (tid & 15)] = v * scale;
        }
    }
}

// ---------------- fallback (R5 kernel, used when ws_size is too small) -----
#define NROWS 12
#define NTASK 1152
#define KS 264
#define RS 1096
#define KSTRIDE (KC * CHW)
#define XBI(row, kg, n) ((row) * RS + (kg) * KS + (n) * 8)

__global__ __launch_bounds__(512, 4) void corr_mfma_fb(
    const float* __restrict__ x1, const float* __restrict__ x2,
    float* __restrict__ out)
{
    __shared__ union {
        unsigned short xb[NROWS * RS];
        float band[4][9][9][18];
    } lds;

    const int lin = blockIdx.x;
    const int sw  = (lin & 7) * 144 + (lin >> 3);
    const int b   = sw / 288;
    const int t2  = sw - b * 288;
    const int ty  = t2 / 12;
    const int tx  = t2 - ty * 12;

    const int tid  = threadIdx.x;
    const int wv   = tid >> 6;
    const int lane = tid & 63;
    const int col  = lane & 15;
    const int q    = lane >> 4;
    const int r    = wv & 3;
    const int dig  = wv >> 2;
    const int w0   = tx * TW;
    const int h0   = ty * 4;
    const int h    = h0 + r;

    f32x4 acc[9];
#pragma unroll
    for (int s = 0; s < 9; ++s) acc[s] = (f32x4)0.0f;

    unsigned o2k[3];
    int      lofk[3];
    bool     okk[3];
    bool     act[3];
#pragma unroll
    for (int k = 0; k < 3; ++k) {
        const int t   = tid + k * 512;
        act[k] = (t < NTASK);
        const int seg = t % 6;
        const int u   = t / 6;
        const int cp  = u & 15;
        const int row = u >> 4;
        const int gh  = h0 - 4 + row;
        const int gw  = w0 - 4 + seg * 4;
        okk[k] = act[k] & (gh >= 0) & (gh < HH) & (gw >= 0) & (gw <= WW - 4);
        const int ghc = gh < 0 ? 0 : (gh > HH - 1 ? HH - 1 : gh);
        const int gwc = gw < 0 ? 0 : gw;
        const int rwc = row > NROWS - 1 ? NROWS - 1 : row;
        o2k[k]  = (unsigned)(((b * NC + cp * 2) * HH + ghc) * WW + gwc);
        lofk[k] = XBI(rwc, cp >> 2, seg * 4) + (cp & 3) * 2;
    }
    unsigned o1 = (unsigned)(((b * NC + q * 8) * HH + h) * WW + w0 + col);

    float pf[24];
    float pa[8];

#define STAGE_LOAD_FB()                                                  \
    {                                                                    \
        _Pragma("unroll")                                                \
        for (int k = 0; k < 3; ++k) {                                    \
            _Pragma("unroll")                                            \
            for (int e = 0; e < 2; ++e) {                                \
                float4 ld = make_float4(0.f, 0.f, 0.f, 0.f);             \
                if (okk[k]) ld = *(const float4*)&x2[o2k[k] + e * CHW];  \
                *(float4*)&pf[(k * 2 + e) * 4] = ld;                     \
            }                                                            \
            o2k[k] += KSTRIDE;                                           \
        }                                                                \
    }

#define X1_LOAD_FB()                                                     \
    {                                                                    \
        _Pragma("unroll")                                                \
        for (int j = 0; j < 8; ++j) pa[j] = x1[o1 + j * CHW];            \
        o1 += KSTRIDE;                                                   \
    }

    STAGE_LOAD_FB();
    X1_LOAD_FB();

    const int rbase = XBI(r, q, col);

    for (int ci = 0; ci < 8; ++ci) {
#pragma unroll
        for (int k = 0; k < 3; ++k) {
            if (act[k]) {
#pragma unroll
                for (int p = 0; p < 4; ++p) {
                    ushort2 v;
                    v.x = f2bf(pf[(k * 2 + 0) * 4 + p]);
                    v.y = f2bf(pf[(k * 2 + 1) * 4 + p]);
                    *(ushort2*)&lds.xb[lofk[k] + p * 8] = v;
                }
            }
        }
        __syncthreads();

        bf16x8 a;
#pragma unroll
        for (int j = 0; j < 8; ++j) a[j] = (short)f2bf(pa[j]);
        if (ci < 7) {
            STAGE_LOAD_FB();
            X1_LOAD_FB();
        }

#pragma unroll
        for (int s = 0; s < 9; ++s) {
            const int u    = dig * 9 + s;
            const int di   = u >> 1;
            const int half = u & 1;
            bf16x8 bb = *(const bf16x8*)&lds.xb[rbase + di * RS + half * 128];
            acc[s] = __builtin_amdgcn_mfma_f32_16x16x32_bf16(a, bb, acc[s], 0, 0, 0);
        }
        __syncthreads();
    }

#pragma unroll
    for (int s = 0; s < 9; ++s) {
        const int u  = dig * 9 + s;
        const int di = u >> 1;
        const int uh = u & 1;
#pragma unroll
        for (int rg = 0; rg < 4; ++rg) {
            int m  = q * 4 + rg;
            int dj = uh * 16 + col - m;
            if (dj >= 0 && dj < 9)
                lds.band[r][di][dj][m] = acc[s][rg];
        }
    }
    __syncthreads();

    const float scale = 1.0f / 256.0f;
#pragma unroll
    for (int it = 0; it < 11; ++it) {
        int gi = it * 32 + (tid >> 4);
        if (gi < 324) {
            int combo = gi >> 2;
            int row   = gi & 3;
            float v = lds.band[row][combo / 9][combo % 9][tid & 15];
            out[((size_t)((b * 81 + combo) * HH + h0 + row)) * WW + w0 + (tid & 15)] = v * scale;
        }
    }
}

extern "C" void kernel_launch(void* const* d_in, const int* in_sizes, int n_in,
                              void* d_out, int out_size, void* d_ws, size_t ws_size,
                              hipStream_t stream) {
    const float* x1 = (const float*)d_in[0];
    const float* x2 = (const float*)d_in[1];
    float* out = (float*)d_out;

    if (ws_size >= XT2_BYTES) {
        unsigned short* ft = (unsigned short*)d_ws;
        pack_x2<<<dim3(NTILES / 4), 256, 0, stream>>>(x2, ft);
        corr_mfma_ft<<<dim3(2304), 256, 0, stream>>>(x1, ft, out);
    } else {
        corr_mfma_fb<<<dim3(1152), 512, 0, stream>>>(x1, x2, out);
    }
}